// Round 1
// baseline (1043.996 us; speedup 1.0000x reference)
//
#include <hip/hip_runtime.h>

// VectorQuantizer forward: inputs [64,2048,64] f32, codebook [1024,64] f32.
// Outputs concatenated in d_out (f32): quantized_ste [8388608], loss [1], indices-as-float [131072].
//
// Numerics contract: must reproduce np/jax fp32 argmin of
//   d2 = sum(x*x) - 2*(x@cb.T) + sum(cb*cb)
// including the coarse fp32 rounding near d2~64 (ties on the ulp grid resolve
// to the FIRST index). So: compute A=sum(x^2) fp32, dot fp32, then
// fl(fl(A - 2*dot) + csq[k]) and scan k ascending with strict '<'.

#define NROWS  131072
#define DIM    64
#define KCB    1024
#define RPB    128          // rows per block
#define KHALF  512
#define QSIZE  (NROWS * DIM)   // 8388608

__global__ __launch_bounds__(256) void vq_prep(const float* __restrict__ cb,
                                               float* __restrict__ csq,
                                               float* __restrict__ loss_slot) {
    int k = blockIdx.x * 256 + threadIdx.x;
    if (k < KCB) {
        const float* c = cb + k * DIM;
        float a0 = 0.f, a1 = 0.f, a2 = 0.f, a3 = 0.f;
        #pragma unroll
        for (int d = 0; d < 16; ++d) {
            a0 = fmaf(c[d],      c[d],      a0);
            a1 = fmaf(c[16 + d], c[16 + d], a1);
            a2 = fmaf(c[32 + d], c[32 + d], a2);
            a3 = fmaf(c[48 + d], c[48 + d], a3);
        }
        csq[k] = (a0 + a1) + (a2 + a3);
    }
    if (blockIdx.x == 0 && threadIdx.x == 0) *loss_slot = 0.f;  // zero loss accumulator every call
}

__global__ __launch_bounds__(256) void vq_main(const float* __restrict__ x,
                                               const float* __restrict__ cb,
                                               const float* __restrict__ csq,
                                               float* __restrict__ out_q,
                                               float* __restrict__ out_loss,
                                               float* __restrict__ out_idx) {
    __shared__ float s_best[2][RPB];
    __shared__ int   s_bidx[2][RPB];
    __shared__ int   s_final[RPB];
    __shared__ float s_loss[4];

    const int tid      = threadIdx.x;
    const int wid      = tid >> 6;       // wave id 0..3
    const int lane     = tid & 63;
    const int rgroup   = wid >> 1;       // which 64-row group (0/1)
    const int khalf    = wid & 1;        // which K half
    const int rowInBlk = rgroup * 64 + lane;
    const int row      = blockIdx.x * RPB + rowInBlk;

    // ---- load this thread's row into registers (256B-aligned float4 loads) ----
    float xr[DIM];
    const float4* xv = reinterpret_cast<const float4*>(x + (size_t)row * DIM);
    #pragma unroll
    for (int i = 0; i < DIM / 4; ++i) {
        float4 v = xv[i];
        xr[4 * i + 0] = v.x; xr[4 * i + 1] = v.y;
        xr[4 * i + 2] = v.z; xr[4 * i + 3] = v.w;
    }

    // ---- A = sum(x^2), fixed order (identical across the wave pair for a row) ----
    float a0 = 0.f, a1 = 0.f, a2 = 0.f, a3 = 0.f;
    #pragma unroll
    for (int d = 0; d < 16; ++d) {
        a0 = fmaf(xr[d],      xr[d],      a0);
        a1 = fmaf(xr[16 + d], xr[16 + d], a1);
        a2 = fmaf(xr[32 + d], xr[32 + d], a2);
        a3 = fmaf(xr[48 + d], xr[48 + d], a3);
    }
    const float A = (a0 + a1) + (a2 + a3);

    // ---- scan this wave's K half; k is wave-uniform -> codebook row via s_load ----
    float best = 3.4e38f;
    int   bidx = 0;
    const int kbase = khalf * KHALF;
    for (int kk = 0; kk < KHALF; ++kk) {
        const int k = kbase + kk;
        const float* __restrict__ c = cb + (size_t)k * DIM;
        float d0 = 0.f, d1 = 0.f, d2c = 0.f, d3 = 0.f;
        #pragma unroll
        for (int d = 0; d < 16; ++d) {
            d0  = fmaf(xr[d],      c[d],      d0);
            d1  = fmaf(xr[16 + d], c[16 + d], d1);
            d2c = fmaf(xr[32 + d], c[32 + d], d2c);
            d3  = fmaf(xr[48 + d], c[48 + d], d3);
        }
        const float dot = (d0 + d1) + (d2c + d3);
        const float t   = A - 2.0f * dot;   // single fp32 rounding (2*dot exact)
        const float d2  = t + csq[k];       // second rounding, matches ref expr
        if (d2 < best) { best = d2; bidx = k; }   // strict '<': first index wins ties
    }

    s_best[khalf][rowInBlk] = best;
    s_bidx[khalf][rowInBlk] = bidx;
    __syncthreads();

    if (khalf == 0) {
        // strict '<' so the low-K half (smaller indices) wins exact ties
        const float b1 = s_best[1][rowInBlk];
        const int   i1 = s_bidx[1][rowInBlk];
        const int  fin = (b1 < best) ? i1 : bidx;
        s_final[rowInBlk] = fin;
        out_idx[row] = (float)fin;
    }
    __syncthreads();

    // ---- epilogue: coalesced STE write + loss partial ----
    const size_t base = (size_t)blockIdx.x * RPB * DIM;
    float lsum = 0.f;
    #pragma unroll 4
    for (int i = tid; i < RPB * DIM; i += 256) {
        const int r = i >> 6;
        const int d = i & 63;
        const int kb = s_final[r];           // wave-uniform within each iteration
        const float q  = cb[(size_t)kb * DIM + d];
        const float xe = x[base + i];
        out_q[base + i] = xe + (q - xe);     // STE forward, ref's rounding
        const float df = q - xe;
        lsum = fmaf(df, df, lsum);
    }
    #pragma unroll
    for (int off = 32; off; off >>= 1) lsum += __shfl_down(lsum, off, 64);
    if (lane == 0) s_loss[wid] = lsum;
    __syncthreads();
    if (tid == 0) {
        const float tot = (s_loss[0] + s_loss[1]) + (s_loss[2] + s_loss[3]);
        atomicAdd(out_loss, tot * (1.25f / 8388608.0f));  // (q_loss + 0.25*e_loss)/count
    }
}

extern "C" void kernel_launch(void* const* d_in, const int* in_sizes, int n_in,
                              void* d_out, int out_size, void* d_ws, size_t ws_size,
                              hipStream_t stream) {
    const float* x  = (const float*)d_in[0];   // 8388608
    const float* cb = (const float*)d_in[1];   // 65536
    float* out      = (float*)d_out;
    float* out_loss = out + QSIZE;             // [8388608]
    float* out_idx  = out + QSIZE + 1;         // [8388609 .. 8519680]
    float* csq      = (float*)d_ws;            // 1024 floats scratch

    vq_prep<<<4, 256, 0, stream>>>(cb, csq, out_loss);
    vq_main<<<NROWS / RPB, 256, 0, stream>>>(x, cb, csq, out, out_loss, out_idx);
}

// Round 2
// 675.676 us; speedup vs baseline: 1.5451x; 1.5451x over previous
//
#include <hip/hip_runtime.h>

// VectorQuantizer forward: inputs [64,2048,64] f32, codebook [1024,64] f32.
// Outputs concatenated in d_out (f32): quantized_ste [8388608], loss [1], indices-as-float [131072].
//
// Round 2: LDS-staged codebook. Round-1 lesson: threadIdx-derived k defeats
// uniformity analysis -> per-lane global_load broadcast storm (VALUBusy 31%).
// Now every thread scans all 1024 codes; codebook comes from LDS tiles
// (wave-uniform address -> hardware broadcast, no bank conflicts).
//
// Numerics contract (verified absmax 0.0 in round 1): fp32 chains
// d0:dims0-15, d1:16-31, d2:32-47, d3:48-63, combined (d0+d1)+(d2+d3);
// d2 = fl(fl(A - 2*dot) + csq[k]); scan k ascending, strict '<' (first min wins).

#define NROWS  131072
#define DIM    64
#define KCB    1024
#define KT     128            // codebook rows per LDS tile
#define NTILES (KCB / KT)     // 8
#define RPB    256            // rows per block = threads per block
#define QSIZE  (NROWS * DIM)  // 8388608

__global__ __launch_bounds__(256) void vq_prep(const float* __restrict__ cb,
                                               float* __restrict__ csq,
                                               float* __restrict__ loss_slot) {
    int k = blockIdx.x * 256 + threadIdx.x;
    if (k < KCB) {
        const float* c = cb + k * DIM;
        float a0 = 0.f, a1 = 0.f, a2 = 0.f, a3 = 0.f;
        #pragma unroll
        for (int d = 0; d < 16; ++d) {
            a0 = fmaf(c[d],      c[d],      a0);
            a1 = fmaf(c[16 + d], c[16 + d], a1);
            a2 = fmaf(c[32 + d], c[32 + d], a2);
            a3 = fmaf(c[48 + d], c[48 + d], a3);
        }
        csq[k] = (a0 + a1) + (a2 + a3);
    }
    if (blockIdx.x == 0 && threadIdx.x == 0) *loss_slot = 0.f;  // zero loss accumulator every call
}

__global__ __launch_bounds__(256) void vq_main(const float* __restrict__ x,
                                               const float* __restrict__ cb,
                                               const float* __restrict__ csq,
                                               float* __restrict__ out_q,
                                               float* __restrict__ out_loss,
                                               float* __restrict__ out_idx) {
    __shared__ float4 s_cb4[KT * DIM / 4];   // 32 KB: one codebook tile
    __shared__ float  s_csq[KCB];            // 4 KB: all code norms
    __shared__ int    s_final[RPB];
    __shared__ float  s_loss[4];

    const int tid  = threadIdx.x;
    const int lane = tid & 63;
    const int wid  = tid >> 6;
    const int row  = blockIdx.x * RPB + tid;

    // stage csq once (4 floats/thread, coalesced)
    #pragma unroll
    for (int j = 0; j < KCB / 256; ++j) s_csq[tid + 256 * j] = csq[tid + 256 * j];

    // ---- load this thread's row into registers ----
    float xr[DIM];
    const float4* xv = reinterpret_cast<const float4*>(x + (size_t)row * DIM);
    #pragma unroll
    for (int i = 0; i < DIM / 4; ++i) {
        float4 v = xv[i];
        xr[4 * i + 0] = v.x; xr[4 * i + 1] = v.y;
        xr[4 * i + 2] = v.z; xr[4 * i + 3] = v.w;
    }

    // ---- A = sum(x^2), same chain order as the passing round ----
    float a0 = 0.f, a1 = 0.f, a2 = 0.f, a3 = 0.f;
    #pragma unroll
    for (int d = 0; d < 16; ++d) {
        a0 = fmaf(xr[d],      xr[d],      a0);
        a1 = fmaf(xr[16 + d], xr[16 + d], a1);
        a2 = fmaf(xr[32 + d], xr[32 + d], a2);
        a3 = fmaf(xr[48 + d], xr[48 + d], a3);
    }
    const float A = (a0 + a1) + (a2 + a3);

    // ---- scan all K in LDS tiles; k is block-uniform -> LDS broadcast ----
    float best = 3.4e38f;
    int   bidx = 0;
    for (int t = 0; t < NTILES; ++t) {
        __syncthreads();   // protect previous tile's readers
        // stage tile t: 2048 float4s, 8 per thread, coalesced
        const float4* gsrc = reinterpret_cast<const float4*>(cb) + t * (KT * DIM / 4);
        #pragma unroll
        for (int j = 0; j < KT * DIM / 4 / 256; ++j)
            s_cb4[tid + 256 * j] = gsrc[tid + 256 * j];
        __syncthreads();

        #pragma unroll 2
        for (int kk = 0; kk < KT; ++kk) {
            const float4* c4 = &s_cb4[kk * (DIM / 4)];
            float d0 = 0.f, d1 = 0.f, d2c = 0.f, d3 = 0.f;
            #pragma unroll
            for (int j = 0; j < 4; ++j) {
                float4 v0 = c4[j];          // dims 4j   .. 4j+3   (0..15)
                float4 v1 = c4[4 + j];      // dims 16+..          (16..31)
                float4 v2 = c4[8 + j];      // (32..47)
                float4 v3 = c4[12 + j];     // (48..63)
                d0  = fmaf(xr[4 * j + 0],      v0.x, d0);
                d0  = fmaf(xr[4 * j + 1],      v0.y, d0);
                d0  = fmaf(xr[4 * j + 2],      v0.z, d0);
                d0  = fmaf(xr[4 * j + 3],      v0.w, d0);
                d1  = fmaf(xr[16 + 4 * j + 0], v1.x, d1);
                d1  = fmaf(xr[16 + 4 * j + 1], v1.y, d1);
                d1  = fmaf(xr[16 + 4 * j + 2], v1.z, d1);
                d1  = fmaf(xr[16 + 4 * j + 3], v1.w, d1);
                d2c = fmaf(xr[32 + 4 * j + 0], v2.x, d2c);
                d2c = fmaf(xr[32 + 4 * j + 1], v2.y, d2c);
                d2c = fmaf(xr[32 + 4 * j + 2], v2.z, d2c);
                d2c = fmaf(xr[32 + 4 * j + 3], v2.w, d2c);
                d3  = fmaf(xr[48 + 4 * j + 0], v3.x, d3);
                d3  = fmaf(xr[48 + 4 * j + 1], v3.y, d3);
                d3  = fmaf(xr[48 + 4 * j + 2], v3.z, d3);
                d3  = fmaf(xr[48 + 4 * j + 3], v3.w, d3);
            }
            const float dot = (d0 + d1) + (d2c + d3);
            const int   k   = t * KT + kk;
            const float tt  = A - 2.0f * dot;    // 2*dot exact; one rounding
            const float dd  = tt + s_csq[k];     // second rounding, ref expr
            if (dd < best) { best = dd; bidx = k; }  // strict '<': first index wins
        }
    }

    s_final[tid] = bidx;
    out_idx[row] = (float)bidx;
    __syncthreads();

    // ---- epilogue: coalesced STE write + loss partial ----
    const size_t base = (size_t)blockIdx.x * RPB * DIM;
    float lsum = 0.f;
    #pragma unroll 4
    for (int i = tid; i < RPB * DIM; i += 256) {
        const int r = i >> 6;
        const int d = i & 63;
        const int kb = s_final[r];
        const float q  = cb[(size_t)kb * DIM + d];
        const float xe = x[base + i];
        out_q[base + i] = xe + (q - xe);     // STE forward, ref's rounding
        const float df = q - xe;
        lsum = fmaf(df, df, lsum);
    }
    #pragma unroll
    for (int off = 32; off; off >>= 1) lsum += __shfl_down(lsum, off, 64);
    if (lane == 0) s_loss[wid] = lsum;
    __syncthreads();
    if (tid == 0) {
        const float tot = (s_loss[0] + s_loss[1]) + (s_loss[2] + s_loss[3]);
        atomicAdd(out_loss, tot * (1.25f / 8388608.0f));  // (q + 0.25*e) / count
    }
}

extern "C" void kernel_launch(void* const* d_in, const int* in_sizes, int n_in,
                              void* d_out, int out_size, void* d_ws, size_t ws_size,
                              hipStream_t stream) {
    const float* x  = (const float*)d_in[0];   // 8388608
    const float* cb = (const float*)d_in[1];   // 65536
    float* out      = (float*)d_out;
    float* out_loss = out + QSIZE;             // [8388608]
    float* out_idx  = out + QSIZE + 1;         // [8388609 .. 8519680]
    float* csq      = (float*)d_ws;            // 1024 floats scratch

    vq_prep<<<4, 256, 0, stream>>>(cb, csq, out_loss);
    vq_main<<<NROWS / RPB, 256, 0, stream>>>(x, cb, csq, out, out_loss, out_idx);
}

// Round 3
// 611.513 us; speedup vs baseline: 1.7072x; 1.1049x over previous
//
#include <hip/hip_runtime.h>

// VectorQuantizer forward: inputs [64,2048,64] f32, codebook [1024,64] f32.
// Outputs concatenated in d_out (f32): quantized_ste [8388608], loss [1], indices-as-float [131072].
//
// Round 3: round-2's VGPR_Count=60 proved the compiler re-loaded the 64-float
// row from memory every k (occupancy heuristic picked 8 waves/EU). The grid
// itself caps at 2 waves/SIMD (2048 waves / 256 CU), so __launch_bounds__(256,2)
// costs nothing and gives the allocator room to keep the row register-resident.
//
// Numerics contract (absmax 0.0 in rounds 1-2): fp32 chains
// d0:dims0-15, d1:16-31, d2:32-47, d3:48-63, combined (d0+d1)+(d2+d3);
// d2 = fl(fl(A - 2*dot) + csq[k]); scan k ascending, strict '<' (first min wins).

#define NROWS  131072
#define DIM    64
#define KCB    1024
#define KT     128            // codebook rows per LDS tile
#define NTILES (KCB / KT)     // 8
#define RPB    256            // rows per block = threads per block
#define QSIZE  (NROWS * DIM)  // 8388608

__global__ __launch_bounds__(256) void vq_prep(const float* __restrict__ cb,
                                               float* __restrict__ csq,
                                               float* __restrict__ loss_slot) {
    int k = blockIdx.x * 256 + threadIdx.x;
    if (k < KCB) {
        const float* c = cb + k * DIM;
        float a0 = 0.f, a1 = 0.f, a2 = 0.f, a3 = 0.f;
        #pragma unroll
        for (int d = 0; d < 16; ++d) {
            a0 = fmaf(c[d],      c[d],      a0);
            a1 = fmaf(c[16 + d], c[16 + d], a1);
            a2 = fmaf(c[32 + d], c[32 + d], a2);
            a3 = fmaf(c[48 + d], c[48 + d], a3);
        }
        csq[k] = (a0 + a1) + (a2 + a3);
    }
    if (blockIdx.x == 0 && threadIdx.x == 0) *loss_slot = 0.f;  // zero loss accumulator every call
}

__global__ __launch_bounds__(256, 2) void vq_main(const float* __restrict__ x,
                                                  const float* __restrict__ cb,
                                                  const float* __restrict__ csq,
                                                  float* __restrict__ out_q,
                                                  float* __restrict__ out_loss,
                                                  float* __restrict__ out_idx) {
    __shared__ float4 s_cb4[KT * DIM / 4];   // 32 KB: one codebook tile
    __shared__ float  s_csq[KCB];            // 4 KB: all code norms
    __shared__ int    s_final[RPB];
    __shared__ float  s_loss[4];

    const int tid  = threadIdx.x;
    const int lane = tid & 63;
    const int wid  = tid >> 6;
    const int row  = blockIdx.x * RPB + tid;

    // stage csq once (4 floats/thread, coalesced)
    #pragma unroll
    for (int j = 0; j < KCB / 256; ++j) s_csq[tid + 256 * j] = csq[tid + 256 * j];

    // ---- load this thread's row into registers (must STAY in registers) ----
    float xr[DIM];
    const float4* xv = reinterpret_cast<const float4*>(x + (size_t)row * DIM);
    #pragma unroll
    for (int i = 0; i < DIM / 4; ++i) {
        float4 v = xv[i];
        xr[4 * i + 0] = v.x; xr[4 * i + 1] = v.y;
        xr[4 * i + 2] = v.z; xr[4 * i + 3] = v.w;
    }

    // ---- A = sum(x^2), same chain order as the passing rounds ----
    float a0 = 0.f, a1 = 0.f, a2 = 0.f, a3 = 0.f;
    #pragma unroll
    for (int d = 0; d < 16; ++d) {
        a0 = fmaf(xr[d],      xr[d],      a0);
        a1 = fmaf(xr[16 + d], xr[16 + d], a1);
        a2 = fmaf(xr[32 + d], xr[32 + d], a2);
        a3 = fmaf(xr[48 + d], xr[48 + d], a3);
    }
    const float A = (a0 + a1) + (a2 + a3);

    // ---- scan all K in LDS tiles; k is block-uniform -> LDS broadcast ----
    float best = 3.4e38f;
    int   bidx = 0;
    for (int t = 0; t < NTILES; ++t) {
        __syncthreads();   // protect previous tile's readers
        // stage tile t: 2048 float4s, 8 per thread, coalesced
        const float4* gsrc = reinterpret_cast<const float4*>(cb) + t * (KT * DIM / 4);
        #pragma unroll
        for (int j = 0; j < KT * DIM / 4 / 256; ++j)
            s_cb4[tid + 256 * j] = gsrc[tid + 256 * j];
        __syncthreads();

        #pragma unroll 4
        for (int kk = 0; kk < KT; ++kk) {
            // explicit register prefetch of the full code row (16 b128 broadcasts)
            float4 c[16];
            #pragma unroll
            for (int j = 0; j < 16; ++j) c[j] = s_cb4[kk * (DIM / 4) + j];

            float d0 = 0.f, d1 = 0.f, d2c = 0.f, d3 = 0.f;
            #pragma unroll
            for (int j = 0; j < 4; ++j) {
                d0  = fmaf(xr[4 * j + 0],      c[j].x,      d0);
                d0  = fmaf(xr[4 * j + 1],      c[j].y,      d0);
                d0  = fmaf(xr[4 * j + 2],      c[j].z,      d0);
                d0  = fmaf(xr[4 * j + 3],      c[j].w,      d0);
                d1  = fmaf(xr[16 + 4 * j + 0], c[4 + j].x,  d1);
                d1  = fmaf(xr[16 + 4 * j + 1], c[4 + j].y,  d1);
                d1  = fmaf(xr[16 + 4 * j + 2], c[4 + j].z,  d1);
                d1  = fmaf(xr[16 + 4 * j + 3], c[4 + j].w,  d1);
                d2c = fmaf(xr[32 + 4 * j + 0], c[8 + j].x,  d2c);
                d2c = fmaf(xr[32 + 4 * j + 1], c[8 + j].y,  d2c);
                d2c = fmaf(xr[32 + 4 * j + 2], c[8 + j].z,  d2c);
                d2c = fmaf(xr[32 + 4 * j + 3], c[8 + j].w,  d2c);
                d3  = fmaf(xr[48 + 4 * j + 0], c[12 + j].x, d3);
                d3  = fmaf(xr[48 + 4 * j + 1], c[12 + j].y, d3);
                d3  = fmaf(xr[48 + 4 * j + 2], c[12 + j].z, d3);
                d3  = fmaf(xr[48 + 4 * j + 3], c[12 + j].w, d3);
            }
            const float dot = (d0 + d1) + (d2c + d3);
            const int   k   = t * KT + kk;
            const float tt  = A - 2.0f * dot;    // 2*dot exact; one rounding
            const float dd  = tt + s_csq[k];     // second rounding, ref expr
            if (dd < best) { best = dd; bidx = k; }  // strict '<': first index wins
        }
    }

    s_final[tid] = bidx;
    out_idx[row] = (float)bidx;
    __syncthreads();

    // ---- epilogue: coalesced STE write + loss partial ----
    const size_t base = (size_t)blockIdx.x * RPB * DIM;
    float lsum = 0.f;
    #pragma unroll 4
    for (int i = tid; i < RPB * DIM; i += 256) {
        const int r = i >> 6;
        const int d = i & 63;
        const int kb = s_final[r];
        const float q  = cb[(size_t)kb * DIM + d];
        const float xe = x[base + i];
        out_q[base + i] = xe + (q - xe);     // STE forward, ref's rounding
        const float df = q - xe;
        lsum = fmaf(df, df, lsum);
    }
    #pragma unroll
    for (int off = 32; off; off >>= 1) lsum += __shfl_down(lsum, off, 64);
    if (lane == 0) s_loss[wid] = lsum;
    __syncthreads();
    if (tid == 0) {
        const float tot = (s_loss[0] + s_loss[1]) + (s_loss[2] + s_loss[3]);
        atomicAdd(out_loss, tot * (1.25f / 8388608.0f));  // (q + 0.25*e) / count
    }
}

extern "C" void kernel_launch(void* const* d_in, const int* in_sizes, int n_in,
                              void* d_out, int out_size, void* d_ws, size_t ws_size,
                              hipStream_t stream) {
    const float* x  = (const float*)d_in[0];   // 8388608
    const float* cb = (const float*)d_in[1];   // 65536
    float* out      = (float*)d_out;
    float* out_loss = out + QSIZE;             // [8388608]
    float* out_idx  = out + QSIZE + 1;         // [8388609 .. 8519680]
    float* csq      = (float*)d_ws;            // 1024 floats scratch

    vq_prep<<<4, 256, 0, stream>>>(cb, csq, out_loss);
    vq_main<<<NROWS / RPB, 256, 0, stream>>>(x, cb, csq, out, out_loss, out_idx);
}